// Round 4
// baseline (3190.747 us; speedup 1.0000x reference)
//
#include <hip/hip_runtime.h>
#include <cstdint>

typedef unsigned short ushort_t;
typedef short v8s __attribute__((ext_vector_type(8)));
typedef float v4f __attribute__((ext_vector_type(4)));
typedef unsigned short v4u __attribute__((ext_vector_type(4)));

#define DMODEL 1024
#define DFF 4096
#define SEQ 4096
#define NBATCH 4
#define NHEAD 16
#define HDIM 64
#define NLAYER 4
#define MTOK (NBATCH*SEQ)   // 16384

#define EPI_QKV 0
#define EPI_RES 3
#define EPI_GELU 4

__device__ __forceinline__ float bf2f(ushort_t u) {
    unsigned v = ((unsigned)u) << 16; float f; __builtin_memcpy(&f, &v, 4); return f;
}
__device__ __forceinline__ ushort_t f2bf(float f) {
    unsigned u; __builtin_memcpy(&u, &f, 4);
    u = (u + 0x7fffu + ((u >> 16) & 1u)) >> 16;
    return (ushort_t)u;
}

// exact-form GELU with A&S 7.1.26 erf approximation (|err| <= 1.5e-7).
__device__ __forceinline__ float gelu_f(float x) {
    const float y = x * 0.70710678118f;
    const float ay = fabsf(y);
    const float t = __builtin_amdgcn_rcpf(1.f + 0.3275911f * ay);
    const float p = t * (0.254829592f + t * (-0.284496736f + t * (1.421413741f +
                    t * (-1.453152027f + t * 1.061405429f))));
    const float e = __expf(-y * y);
    float er = 1.f - p * e;
    er = (y < 0.f) ? -er : er;
    return 0.5f * x * (1.f + er);
}

// direct global->LDS (16B/lane). LDS dest is wave-uniform base + lane*16.
__device__ __forceinline__ void gload16(const ushort_t* g, ushort_t* l) {
    __builtin_amdgcn_global_load_lds(
        (__attribute__((address_space(1))) unsigned int*)g,
        (__attribute__((address_space(3))) unsigned int*)l, 16, 0, 0);
}

// ---------------------------------------------------------------------------
__global__ __launch_bounds__(256) void cvt_bf16(const float* __restrict__ in,
                                                ushort_t* __restrict__ out, int n) {
    int i = (blockIdx.x * 256 + threadIdx.x) * 4;
    if (i >= n) return;
    float4 v = *(const float4*)(in + i);
    v4u o;
    o[0] = f2bf(v.x); o[1] = f2bf(v.y); o[2] = f2bf(v.z); o[3] = f2bf(v.w);
    *(v4u*)(out + i) = o;
}

// pack Wq/Wk/Wv (each [L][D][D] fp32) into bf16 [L][3][D][D]
__global__ __launch_bounds__(256) void cvt_qkv(const float* __restrict__ Wq,
                                               const float* __restrict__ Wk,
                                               const float* __restrict__ Wv,
                                               ushort_t* __restrict__ out) {
    const size_t DD = (size_t)DMODEL * DMODEL;
    size_t i = ((size_t)blockIdx.x * 256 + threadIdx.x) * 4;
    int l = (int)(i / DD);
    size_t r = i % DD;
    const float* srcs[3] = { Wq + l * DD + r, Wk + l * DD + r, Wv + l * DD + r };
    #pragma unroll
    for (int s = 0; s < 3; s++) {
        float4 v = *(const float4*)srcs[s];
        v4u o;
        o[0] = f2bf(v.x); o[1] = f2bf(v.y); o[2] = f2bf(v.z); o[3] = f2bf(v.w);
        *(v4u*)(out + ((size_t)l * 3 + s) * DD + r) = o;
    }
}

// ---------------------------------------------------------------------------
__global__ __launch_bounds__(256) void lens_kernel(const unsigned char* __restrict__ mask,
                                                   int* __restrict__ lens) {
    int lane = threadIdx.x & 63, w = threadIdx.x >> 6;
    int cnt = 0;
    for (int i = lane; i < SEQ; i += 64) cnt += (mask[w * SEQ + i] != 0) ? 1 : 0;
    #pragma unroll
    for (int off = 32; off; off >>= 1) cnt += __shfl_down(cnt, off);
    if (lane == 0) lens[w] = SEQ - cnt;
}

// ---------------------------------------------------------------------------
// GEMM: C[M,N] = A[M,K] @ B[N,K]^T, bf16 in, fp32 acc, fused epilogues.
// 256x256 tile, BK=64, 8 waves of 128x64 each (512 threads).
// R4 schedule: rotated software pipeline, ONE barrier per K-tile.
//  - Next tile's A0/A1 fragments are prefetched into the registers freed by
//    this tile's Q0/Q1 (no VGPR growth: 124+128acc = 252 <= 256, the
//    2-waves/SIMD cap). Next B is prefetched after Q3 (bfr live thru Q3).
//  - Single mid-tile barrier: BOTH conditions are satisfied before it:
//      vmcnt(0)  -> tile t+1 landed (loads issued a full tile ago: ~free)
//      lgkmcnt(0)-> my A2/A3 reads of buf p retired (hidden under Q1 MFMA)
//    After the barrier: buf p^1 is published to all waves AND buf p is safe
//    to overwrite -> ISSUE(t+2, p) + next-tile fragment reads.
//  - Tile boundary no longer drains the pipe: Q0 of tile t+1 finds its A
//    fragments resident; only B's 8 reads are in flight (issued after Q3).
//  - s_setprio(1) around each MFMA cluster (T5).
// global_load_lds staging, LDS linear dest + XOR-pre-swizzled global source;
// read side applies the same XOR -> 0 bank conflicts (verified R2/R3).
// LDS 128 KiB -> 1 block/CU, 2 waves/SIMD.
// ---------------------------------------------------------------------------
#define BAR()    asm volatile("s_barrier" ::: "memory")
#define WAITL0() asm volatile("s_waitcnt lgkmcnt(0)" ::: "memory")
#define WAITV8() asm volatile("s_waitcnt vmcnt(8)" ::: "memory")
#define WAITV0() asm volatile("s_waitcnt vmcnt(0)" ::: "memory")

template <int EPI>
__global__ __launch_bounds__(512, 2) void gemm_bt(
    const ushort_t* __restrict__ A, const ushort_t* __restrict__ B,
    const float* __restrict__ bias, const float* __restrict__ bias2,
    const float* __restrict__ bias3, const float* res,
    const int* __restrict__ lens,
    ushort_t* __restrict__ outB, ushort_t* __restrict__ outB2,
    ushort_t* __restrict__ outB3, float* outF,
    int M, int N, int K)
{
    __shared__ __align__(16) ushort_t As[2][256 * 64];
    __shared__ __align__(16) ushort_t Bs[2][256 * 64];

    const int tid = threadIdx.x;
    const int lane = tid & 63;
    const int w = tid >> 6;          // 0..7
    const int wm = w >> 2;           // 0..1 : row half (128 rows)
    const int wn = w & 3;            // 0..3 : col quarter (64 cols)
    const int nb = N >> 8;
    // XCD-aware remap (dispatch round-robins XCD = blockIdx.x % 8)
    const int xcd = blockIdx.x & 7;
    const int q = blockIdx.x >> 3;
    const int bm = (q / nb) * 8 + xcd;   // M/256 = 64, divisible by 8
    const int bn = q % nb;
    const int lr = lane & 15;
    const int lq = lane >> 4;  // 0..3

    v4f acc[8][4];
    #pragma unroll
    for (int i = 0; i < 8; i++)
        #pragma unroll
        for (int j = 0; j < 4; j++) acc[i][j] = (v4f)0.f;

    // ---- staging geometry ---------------------------------------------
    // A tile = 256 rows x 64 k (row-major, 8 chunks of 8 bf16 per row).
    // LDS slot s of row r holds global chunk s ^ (r&7)  (bank-spread XOR).
    // gload_lds writes LDS linearly (base + lane*16B), so the XOR is applied
    // to the per-lane GLOBAL source address instead:
    //   wave-chunk c (1024B) covers rows c*8..c*8+7; lane l -> row c*8+(l>>3),
    //   slot l&7  => global chunk (l&7)^(l>>3).
    const int srow = lane >> 3;            // 0..7
    const int schunk = (lane & 7) ^ srow;  // pre-swizzled source chunk
    const ushort_t* Ag = A + (size_t)(bm * 256 + srow) * K + schunk * 8;
    const ushort_t* Bg = B + (size_t)(bn * 256 + srow) * K + schunk * 8;

    // ---- read-side fragment offsets (k-invariant, read-side XOR) ------
    // A frag (quad qq, rowfrag i, khalf kh): row ra = wm*128+qq*32+i*16+lr,
    // global chunk kh*4+lq, LDS slot (kh*4+lq)^(ra&7); ra&7 == lr&7.
    int aoff[2], boff[2];
    #pragma unroll
    for (int kh = 0; kh < 2; kh++) {
        aoff[kh] = (wm * 128 + lr) * 64 + (((kh * 4 + lq) ^ (lr & 7)) * 8);
        boff[kh] = (wn * 64 + lr) * 64 + (((kh * 4 + lq) ^ (lr & 7)) * 8);
    }

    const int KT = K >> 6;

    // fragment register sets (rotated across tiles; no extra sets -> no
    // VGPR growth; WAR on reuse is handled by the compiler's hazard logic)
    v8s bfr[4][2];
    v8s af0[2][2], af1[2][2], af2[2][2], af3[2][2];

#define ISSUE_TILE(T_, P_) do { \
    const size_t kk_ = (size_t)(T_) << 6; \
    _Pragma("unroll") \
    for (int i_ = 0; i_ < 4; i_++) { \
        const int c_ = (w << 2) + i_; \
        gload16(Ag + (size_t)c_ * 8 * K + kk_, &As[P_][c_ << 9]); \
        gload16(Bg + (size_t)c_ * 8 * K + kk_, &Bs[P_][c_ << 9]); \
    } \
} while (0)

#define READ_B(P_) do { \
    _Pragma("unroll") \
    for (int j_ = 0; j_ < 4; j_++) \
        _Pragma("unroll") \
        for (int kh_ = 0; kh_ < 2; kh_++) \
            bfr[j_][kh_] = *(const v8s*)&Bs[P_][boff[kh_] + j_ * 1024]; \
} while (0)

#define READ_AQ(P_, QQ, AF) do { \
    _Pragma("unroll") \
    for (int i_ = 0; i_ < 2; i_++) \
        _Pragma("unroll") \
        for (int kh_ = 0; kh_ < 2; kh_++) \
            AF[i_][kh_] = *(const v8s*)&As[P_][aoff[kh_] + (QQ) * 2048 + i_ * 1024]; \
} while (0)

#define MFMA_Q(QQ, AF) do { \
    __builtin_amdgcn_s_setprio(1); \
    _Pragma("unroll") \
    for (int i_ = 0; i_ < 2; i_++) \
        _Pragma("unroll") \
        for (int j_ = 0; j_ < 4; j_++) \
            _Pragma("unroll") \
            for (int kh_ = 0; kh_ < 2; kh_++) \
                acc[(QQ) * 2 + i_][j_] = __builtin_amdgcn_mfma_f32_16x16x32_bf16( \
                    AF[i_][kh_], bfr[j_][kh_], acc[(QQ) * 2 + i_][j_], 0, 0, 0); \
    __builtin_amdgcn_s_setprio(0); \
} while (0)

// one K-tile, rotated pipeline, ONE barrier per tile.
// entry state: af0/af1/bfr hold tile T_'s fragments (issued last body);
// buf Q_ = P_^1 holds tile T_+1 (landing), its loads are the only vmem.
#define TILE_BODY(T_, P_, Q_) do { \
    MFMA_Q(0, af0); \
    READ_AQ(P_, 2, af2); \
    READ_AQ(P_, 3, af3); \
    MFMA_Q(1, af1); \
    if ((T_) + 1 < KT) { \
        WAITV0();            /* tile T_+1 landed (loads are a tile old) */ \
        WAITL0();            /* my A2/A3 reads of buf P_ retired */ \
        BAR();               /* publish T_+1 AND license overwrite of P_ */ \
        if ((T_) + 2 < KT) ISSUE_TILE((T_) + 2, P_); \
        READ_AQ(Q_, 0, af0); /* next tile's A0/A1 into freed regs */ \
        READ_AQ(Q_, 1, af1); \
    } \
    MFMA_Q(2, af2); \
    MFMA_Q(3, af3); \
    if ((T_) + 1 < KT) READ_B(Q_);   /* bfr free after Q3 */ \
} while (0)

    // prologue: tiles 0 and 1 in flight; tile 0 confirmed + published,
    // tile 0's B/A0/A1 fragment reads issued.
    ISSUE_TILE(0, 0);
    ISSUE_TILE(1, 1);
    WAITV8();
    BAR();
    READ_B(0);
    READ_AQ(0, 0, af0);
    READ_AQ(0, 1, af1);

    for (int t = 0; t < KT; t += 2) {   // KT is even (K = 1024 or 4096)
        TILE_BODY(t, 0, 1);
        TILE_BODY(t + 1, 1, 0);
    }

#undef TILE_BODY
#undef MFMA_Q
#undef READ_AQ
#undef READ_B
#undef ISSUE_TILE

    // epilogue: C/D layout col = lane&15, row = (lane>>4)*4 + reg
    const int row0 = bm * 256 + wm * 128 + lq * 4;
    const int col0 = bn * 256 + wn * 64 + lr;

    const int seg = (EPI == EPI_QKV) ? (bn >> 2) : 0;   // 1024-col segments
    ushort_t* qkv_out = (EPI == EPI_QKV)
        ? (seg == 0 ? outB : (seg == 1 ? outB2 : outB3)) : outB;
    const float* qkv_bias = (EPI == EPI_QKV)
        ? (seg == 0 ? bias : (seg == 1 ? bias2 : bias3)) : bias;
    const int blen = (EPI == EPI_QKV) ? lens[bm >> 4] : 0;

    #pragma unroll
    for (int i = 0; i < 8; i++) {
        #pragma unroll
        for (int j = 0; j < 4; j++) {
            const int gn = col0 + j * 16;
            const float bsv = (EPI == EPI_QKV) ? qkv_bias[gn & 1023] : bias[gn];
            #pragma unroll
            for (int r = 0; r < 4; r++) {
                const int gm = row0 + i * 16 + r;
                float v = acc[i][j][r] + bsv;
                if (EPI == EPI_QKV) {
                    const size_t oi = (size_t)gm * DMODEL + (gn & 1023);
                    if (seg == 2) {
                        qkv_out[oi] = f2bf(v);                    // V
                    } else {
                        float e = v > 0.f ? v + 1.f : __expf(v);  // elu+1
                        if (seg == 1 && (gm & 4095) >= blen) e = 0.f;  // K mask
                        qkv_out[oi] = f2bf(e);
                    }
                } else if (EPI == EPI_RES) {
                    const size_t oi = (size_t)gm * N + gn;
                    outF[oi] = v + res[oi];
                } else {  // EPI_GELU
                    const size_t oi = (size_t)gm * N + gn;
                    outB[oi] = f2bf(gelu_f(v));
                }
            }
        }
    }
}

// ---------------------------------------------------------------------------
__global__ __launch_bounds__(256) void ksum_kernel(const ushort_t* __restrict__ K,
                                                   float* __restrict__ out) {
    const int blk = blockIdx.x;
    const int n = blk >> 4, cg = blk & 15;
    const int tx = threadIdx.x & 63, ty = threadIdx.x >> 6;
    const int col = cg * 64 + tx;
    const ushort_t* p = K + ((size_t)n * SEQ + ty * 1024) * DMODEL + col;
    float a = 0.f;
    for (int s = 0; s < 1024; s++) a += bf2f(p[(size_t)s * DMODEL]);
    __shared__ float red[4][64];
    red[ty][tx] = a;
    __syncthreads();
    if (ty == 0) out[n * DMODEL + col] = red[0][tx] + red[1][tx] + red[2][tx] + red[3][tx];
}

// ---------------------------------------------------------------------------
__global__ __launch_bounds__(256) void kv_part(const ushort_t* __restrict__ K,
                                               const ushort_t* __restrict__ V,
                                               float* __restrict__ part) {
    const int chunk = blockIdx.x, nh = blockIdx.y;
    const int n = nh >> 4, h = nh & 15;
    const int tid = threadIdx.x;
    const int tm = tid >> 4, td = tid & 15;
    __shared__ float Ks[16][68];
    __shared__ float Vs[16][68];
    float acc[4][4] = {};
    const int s0 = chunk * 512;
    for (int sb = 0; sb < 512; sb += 16) {
        __syncthreads();
        for (int idx = tid; idx < 1024; idx += 256) {
            const int r = idx >> 6, c = idx & 63;
            const size_t gpos = ((size_t)(n * SEQ + s0 + sb + r)) * DMODEL + h * HDIM + c;
            Ks[r][c] = bf2f(K[gpos]);
            Vs[r][c] = bf2f(V[gpos]);
        }
        __syncthreads();
        #pragma unroll
        for (int s = 0; s < 16; s++) {
            float kv[4], vv[4];
            #pragma unroll
            for (int j = 0; j < 4; j++) kv[j] = Ks[s][td * 4 + j];
            #pragma unroll
            for (int i = 0; i < 4; i++) vv[i] = Vs[s][tm * 4 + i];
            #pragma unroll
            for (int i = 0; i < 4; i++)
                #pragma unroll
                for (int j = 0; j < 4; j++)
                    acc[i][j] += vv[i] * kv[j];
        }
    }
    float* o = part + ((size_t)chunk * 64 + nh) * 4096;
    #pragma unroll
    for (int i = 0; i < 4; i++)
        #pragma unroll
        for (int j = 0; j < 4; j++)
            o[(tm * 4 + i) * 64 + td * 4 + j] = acc[i][j];
}

__global__ __launch_bounds__(256) void kv_reduce(const float* __restrict__ part,
                                                 float* __restrict__ KV) {
    const int gid = blockIdx.x * 256 + threadIdx.x;
    float a = 0.f;
    #pragma unroll
    for (int c = 0; c < 8; c++) a += part[(size_t)c * (64 * 4096) + gid];
    KV[gid] = a;
}

// ---------------------------------------------------------------------------
__global__ __launch_bounds__(256) void attn_kernel(const ushort_t* __restrict__ Q,
                                                   const float* __restrict__ KV,
                                                   const float* __restrict__ Ksum,
                                                   ushort_t* __restrict__ out) {
    const int bx = blockIdx.x, nh = blockIdx.y;
    const int n = nh >> 4, h = nh & 15;
    const int tid = threadIdx.x;
    const int ty = tid >> 4, tx = tid & 15;
    __shared__ float KVs[64][65];
    __shared__ float Qs[64][65];
    __shared__ float Zs[64];
    const int t0 = n * SEQ + bx * 64;
    for (int idx = tid; idx < 4096; idx += 256) {
        const int r = idx >> 6, c = idx & 63;
        KVs[r][c] = KV[(size_t)nh * 4096 + idx];
        Qs[r][c] = bf2f(Q[((size_t)(t0 + r)) * DMODEL + h * HDIM + c]);
    }
    __syncthreads();
    if (tid < 64) {
        const float* ks = Ksum + n * DMODEL + h * HDIM;
        float a = 0.f;
        #pragma unroll
        for (int d = 0; d < 64; d++) a += Qs[tid][d] * ks[d];
        Zs[tid] = 1.f / (a + 1e-6f);
    }
    __syncthreads();
    float acc[4][4] = {};
    for (int d = 0; d < 64; d++) {
        float qv[4], kv[4];
        #pragma unroll
        for (int i = 0; i < 4; i++) qv[i] = Qs[ty * 4 + i][d];
        #pragma unroll
        for (int j = 0; j < 4; j++) kv[j] = KVs[tx * 4 + j][d];
        #pragma unroll
        for (int i = 0; i < 4; i++)
            #pragma unroll
            for (int j = 0; j < 4; j++)
                acc[i][j] += qv[i] * kv[j];
    }
    #pragma unroll
    for (int i = 0; i < 4; i++) {
        const int r = ty * 4 + i;
        const float z = Zs[r];
        v4u o;
        #pragma unroll
        for (int j = 0; j < 4; j++) o[j] = f2bf(acc[i][j] * z);
        *(v4u*)&out[((size_t)(t0 + r)) * DMODEL + h * HDIM + tx * 4] = o;  // 8B store
    }
}

// ---------------------------------------------------------------------------
__global__ __launch_bounds__(256) void ln_kernel(const float* in, float* outF,
                                                 ushort_t* outB,
                                                 const float* __restrict__ g,
                                                 const float* __restrict__ b) {
    const int row = blockIdx.x;
    const int tid = threadIdx.x;
    const float4 v = ((const float4*)(in + (size_t)row * DMODEL))[tid];
    float s = v.x + v.y + v.z + v.w;
    float ss = v.x * v.x + v.y * v.y + v.z * v.z + v.w * v.w;
    #pragma unroll
    for (int off = 32; off; off >>= 1) {
        s += __shfl_down(s, off);
        ss += __shfl_down(ss, off);
    }
    __shared__ float red[8];
    const int lane = tid & 63, w = tid >> 6;
    if (lane == 0) { red[w * 2] = s; red[w * 2 + 1] = ss; }
    __syncthreads();
    s = red[0] + red[2] + red[4] + red[6];
    ss = red[1] + red[3] + red[5] + red[7];
    const float mu = s * (1.f / DMODEL);
    const float var = ss * (1.f / DMODEL) - mu * mu;
    const float rs = rsqrtf(var + 1e-5f);
    const float4 gg = ((const float4*)g)[tid];
    const float4 bb = ((const float4*)b)[tid];
    float4 o;
    o.x = (v.x - mu) * rs * gg.x + bb.x;
    o.y = (v.y - mu) * rs * gg.y + bb.y;
    o.z = (v.z - mu) * rs * gg.z + bb.z;
    o.w = (v.w - mu) * rs * gg.w + bb.w;
    ((float4*)(outF + (size_t)row * DMODEL))[tid] = o;
    if (outB) {
        v4u ob;
        ob[0] = f2bf(o.x); ob[1] = f2bf(o.y); ob[2] = f2bf(o.z); ob[3] = f2bf(o.w);
        *(v4u*)(outB + (size_t)row * DMODEL + tid * 4) = ob;
    }
}

// ---------------------------------------------------------------------------
extern "C" void kernel_launch(void* const* d_in, const int* in_sizes, int n_in,
                              void* d_out, int out_size, void* d_ws, size_t ws_size,
                              hipStream_t stream) {
    const float* src = (const float*)d_in[0];
    const unsigned char* mask = (const unsigned char*)d_in[1];
    const float* Wq = (const float*)d_in[2];
    const float* bq = (const float*)d_in[3];
    const float* Wk = (const float*)d_in[4];
    const float* bk = (const float*)d_in[5];
    const float* Wv = (const float*)d_in[6];
    const float* bv = (const float*)d_in[7];
    const float* Wo = (const float*)d_in[8];
    const float* bo = (const float*)d_in[9];
    const float* W1 = (const float*)d_in[10];
    const float* b1 = (const float*)d_in[11];
    const float* W2 = (const float*)d_in[12];
    const float* b2 = (const float*)d_in[13];
    const float* g1 = (const float*)d_in[14];
    const float* be1 = (const float*)d_in[15];
    const float* g2 = (const float*)d_in[16];
    const float* be2 = (const float*)d_in[17];

    float* xout = (float*)d_out;  // fp32 residual-stream master

    char* ws = (char*)d_ws;
    size_t off = 0;
    auto alloc = [&](size_t bytes) -> void* {
        void* p = (void*)(ws + off);
        off += (bytes + 255) & ~(size_t)255;
        return p;
    };
    const size_t DD = (size_t)DMODEL * DMODEL;
    const size_t FD = (size_t)DFF * DMODEL;
    const size_t MD = (size_t)MTOK * DMODEL;

    ushort_t* wqkv_bf = (ushort_t*)alloc(NLAYER * 3 * DD * 2);  // [L][3][D][D]
    ushort_t* wo_bf = (ushort_t*)alloc(NLAYER * DD * 2);
    ushort_t* w1r = (ushort_t*)alloc(FD * 2);
    ushort_t* w2r = (ushort_t*)alloc(FD * 2);
    ushort_t* xbf = (ushort_t*)alloc(MD * 2);
    ushort_t* Qb = (ushort_t*)alloc(MD * 2);
    ushort_t* Kb = (ushort_t*)alloc(MD * 2);
    ushort_t* Vb = (ushort_t*)alloc(MD * 2);
    (void)alloc(MD * 2);          // hb (=Qb) overlay spans MTOK*DFF bf16
    ushort_t* hb = Qb;
    float* Ksum = (float*)alloc((size_t)NBATCH * DMODEL * 4);
    float* KVp = (float*)alloc((size_t)8 * 64 * 4096 * 4);
    float* KVb = (float*)alloc((size_t)64 * 4096 * 4);
    int* lens = (int*)alloc(256);
    if (off > ws_size) return;

    cvt_qkv<<<dim3((unsigned)((NLAYER * DD) / 1024)), dim3(256), 0, stream>>>(Wq, Wk, Wv, wqkv_bf);
    cvt_bf16<<<dim3((unsigned)((NLAYER * DD) / 1024)), dim3(256), 0, stream>>>(Wo, wo_bf, (int)(NLAYER * DD));
    lens_kernel<<<dim3(1), dim3(256), 0, stream>>>(mask, lens);
    cvt_bf16<<<dim3((unsigned)(MD / 1024)), dim3(256), 0, stream>>>(src, xbf, (int)MD);

    const dim3 blk(256);
    const dim3 blkG(512);
    const dim3 gQKV((MTOK / 256) * (3 * DMODEL / 256));  // 768 blocks
    const dim3 gD((MTOK / 256) * (DMODEL / 256));        // 256 blocks
    const dim3 gF((MTOK / 256) * (DFF / 256));           // 1024 blocks

    for (int l = 0; l < NLAYER; l++) {
        const ushort_t* wqkvl = wqkv_bf + (size_t)l * 3 * DD;
        const ushort_t* wol = wo_bf + l * DD;
        const float* bql = bq + l * DMODEL;
        const float* bkl = bk + l * DMODEL;
        const float* bvl = bv + l * DMODEL;
        const float* bol = bo + l * DMODEL;
        const float* b1l = b1 + l * DFF;
        const float* b2l = b2 + l * DMODEL;
        const float* g1l = g1 + l * DMODEL;
        const float* be1l = be1 + l * DMODEL;
        const float* g2l = g2 + l * DMODEL;
        const float* be2l = be2 + l * DMODEL;
        const float* resx = (l == 0) ? src : xout;

        // fused Q/K/V projection with feature map + mask
        gemm_bt<EPI_QKV><<<gQKV, blkG, 0, stream>>>(xbf, wqkvl, bql, bkl, bvl,
            nullptr, lens, Qb, Kb, Vb, nullptr, MTOK, 3 * DMODEL, DMODEL);

        // linear-attention core
        ksum_kernel<<<dim3(64), blk, 0, stream>>>(Kb, Ksum);
        kv_part<<<dim3(8, 64), blk, 0, stream>>>(Kb, Vb, KVp);
        kv_reduce<<<dim3(64 * 4096 / 256), blk, 0, stream>>>(KVp, KVb);
        attn_kernel<<<dim3(64, 64), blk, 0, stream>>>(Qb, KVb, Ksum, Kb);  // attn -> Kb

        // output projection + residual (fp32), then LN1 + bf16 copy
        gemm_bt<EPI_RES><<<gD, blkG, 0, stream>>>(Kb, wol, bol, nullptr, nullptr,
            resx, lens, nullptr, nullptr, nullptr, xout, MTOK, DMODEL, DMODEL);
        ln_kernel<<<dim3(MTOK), blk, 0, stream>>>(xout, xout, xbf, g1l, be1l);

        // FFN
        cvt_bf16<<<dim3((unsigned)(FD / 1024)), blk, 0, stream>>>(W1 + l * FD, w1r, (int)FD);
        gemm_bt<EPI_GELU><<<gF, blkG, 0, stream>>>(xbf, w1r, b1l, nullptr, nullptr,
            nullptr, lens, hb, nullptr, nullptr, nullptr, MTOK, DFF, DMODEL);
        cvt_bf16<<<dim3((unsigned)(FD / 1024)), blk, 0, stream>>>(W2 + l * FD, w2r, (int)FD);
        gemm_bt<EPI_RES><<<gD, blkG, 0, stream>>>(hb, w2r, b2l, nullptr, nullptr,
            xout, lens, nullptr, nullptr, nullptr, xout, MTOK, DMODEL, DFF);
        ln_kernel<<<dim3(MTOK), blk, 0, stream>>>(xout, xout, (l == NLAYER - 1) ? nullptr : xbf, g2l, be2l);
    }
}

// Round 5
// 3024.446 us; speedup vs baseline: 1.0550x; 1.0550x over previous
//
#include <hip/hip_runtime.h>
#include <cstdint>

typedef unsigned short ushort_t;
typedef short v8s __attribute__((ext_vector_type(8)));
typedef float v4f __attribute__((ext_vector_type(4)));
typedef unsigned short v4u __attribute__((ext_vector_type(4)));

#define DMODEL 1024
#define DFF 4096
#define SEQ 4096
#define NBATCH 4
#define NHEAD 16
#define HDIM 64
#define NLAYER 4
#define MTOK (NBATCH*SEQ)   // 16384

#define EPI_QKV 0
#define EPI_RES 3
#define EPI_GELU 4

__device__ __forceinline__ float bf2f(ushort_t u) {
    unsigned v = ((unsigned)u) << 16; float f; __builtin_memcpy(&f, &v, 4); return f;
}
__device__ __forceinline__ ushort_t f2bf(float f) {
    unsigned u; __builtin_memcpy(&u, &f, 4);
    u = (u + 0x7fffu + ((u >> 16) & 1u)) >> 16;
    return (ushort_t)u;
}

// exact-form GELU with A&S 7.1.26 erf approximation (|err| <= 1.5e-7).
__device__ __forceinline__ float gelu_f(float x) {
    const float y = x * 0.70710678118f;
    const float ay = fabsf(y);
    const float t = __builtin_amdgcn_rcpf(1.f + 0.3275911f * ay);
    const float p = t * (0.254829592f + t * (-0.284496736f + t * (1.421413741f +
                    t * (-1.453152027f + t * 1.061405429f))));
    const float e = __expf(-y * y);
    float er = 1.f - p * e;
    er = (y < 0.f) ? -er : er;
    return 0.5f * x * (1.f + er);
}

// direct global->LDS (16B/lane). LDS dest is wave-uniform base + lane*16.
__device__ __forceinline__ void gload16(const ushort_t* g, ushort_t* l) {
    __builtin_amdgcn_global_load_lds(
        (__attribute__((address_space(1))) unsigned int*)g,
        (__attribute__((address_space(3))) unsigned int*)l, 16, 0, 0);
}

// ---------------------------------------------------------------------------
__global__ __launch_bounds__(256) void cvt_bf16(const float* __restrict__ in,
                                                ushort_t* __restrict__ out, int n) {
    int i = (blockIdx.x * 256 + threadIdx.x) * 4;
    if (i >= n) return;
    float4 v = *(const float4*)(in + i);
    v4u o;
    o[0] = f2bf(v.x); o[1] = f2bf(v.y); o[2] = f2bf(v.z); o[3] = f2bf(v.w);
    *(v4u*)(out + i) = o;
}

// pack Wq/Wk/Wv (each [L][D][D] fp32) into bf16 [L][3][D][D]
__global__ __launch_bounds__(256) void cvt_qkv(const float* __restrict__ Wq,
                                               const float* __restrict__ Wk,
                                               const float* __restrict__ Wv,
                                               ushort_t* __restrict__ out) {
    const size_t DD = (size_t)DMODEL * DMODEL;
    size_t i = ((size_t)blockIdx.x * 256 + threadIdx.x) * 4;
    int l = (int)(i / DD);
    size_t r = i % DD;
    const float* srcs[3] = { Wq + l * DD + r, Wk + l * DD + r, Wv + l * DD + r };
    #pragma unroll
    for (int s = 0; s < 3; s++) {
        float4 v = *(const float4*)srcs[s];
        v4u o;
        o[0] = f2bf(v.x); o[1] = f2bf(v.y); o[2] = f2bf(v.z); o[3] = f2bf(v.w);
        *(v4u*)(out + ((size_t)l * 3 + s) * DD + r) = o;
    }
}

// ---------------------------------------------------------------------------
__global__ __launch_bounds__(256) void lens_kernel(const unsigned char* __restrict__ mask,
                                                   int* __restrict__ lens) {
    int lane = threadIdx.x & 63, w = threadIdx.x >> 6;
    int cnt = 0;
    for (int i = lane; i < SEQ; i += 64) cnt += (mask[w * SEQ + i] != 0) ? 1 : 0;
    #pragma unroll
    for (int off = 32; off; off >>= 1) cnt += __shfl_down(cnt, off);
    if (lane == 0) lens[w] = SEQ - cnt;
}

// ---------------------------------------------------------------------------
// GEMM: C[M,N] = A[M,K] @ B[N,K]^T, bf16 in, fp32 acc, fused epilogues.
// R5: revert to the PROVEN m97 structure (874-912 TF ref-checked on this
// chip at this shape class, learn_hip m97/m103):
//   128x128 tile, BK=64, 4 waves of 64x64 (256 threads),
//   global_load_lds(16B) staging into a SINGLE 32 KiB LDS buffer,
//   plain 2x __syncthreads per K-step (compiler emits the vmcnt drain).
// Mechanism: small LDS + ~128 VGPR -> 3-4 blocks/CU; cross-block implicit
// wave overlap (m114) absorbs the barrier-drain stall that R2-R4's 1-block
// 256^2 schedules could not hide (three schedules all ~28% MfmaUtil).
// XOR chunk swizzle retained on BOTH sides (source-preswizzle + read XOR)
// -> 0 bank conflicts (verified R2-R4). XCD-aware remap retained.
// No setprio (null on lockstep structures, m190).
// ---------------------------------------------------------------------------
template <int EPI>
__global__ __launch_bounds__(256, 4) void gemm_bt(
    const ushort_t* __restrict__ A, const ushort_t* __restrict__ B,
    const float* __restrict__ bias, const float* __restrict__ bias2,
    const float* __restrict__ bias3, const float* res,
    const int* __restrict__ lens,
    ushort_t* __restrict__ outB, ushort_t* __restrict__ outB2,
    ushort_t* __restrict__ outB3, float* outF,
    int M, int N, int K)
{
    __shared__ __align__(16) ushort_t As[128 * 64];
    __shared__ __align__(16) ushort_t Bs[128 * 64];

    const int tid = threadIdx.x;
    const int lane = tid & 63;
    const int wave = tid >> 6;
    const int nb = N >> 7;
    // XCD-aware remap (dispatch round-robins XCD = blockIdx.x % 8)
    const int xcd = blockIdx.x & 7;
    const int q = blockIdx.x >> 3;
    const int bm = (q / nb) * 8 + xcd;   // M/128 = 128, divisible by 8
    const int bn = q % nb;
    const int wm = (wave >> 1) * 64;
    const int wn = (wave & 1) * 64;
    const int lr = lane & 15;
    const int lq = lane >> 4;  // 0..3

    v4f acc[4][4];
    #pragma unroll
    for (int i = 0; i < 4; i++)
        #pragma unroll
        for (int j = 0; j < 4; j++) acc[i][j] = (v4f)0.f;

    // staging geometry: thread tid writes 16B at LDS element tid*8
    // (row tid/8, slot tid%8); round i covers rows i*32..i*32+31.
    // LDS slot s of row r holds global chunk s^(r&7): pre-swizzled source.
    const int srow = tid >> 3;               // 0..31
    const int schunk = (tid & 7) ^ (srow & 7);
    const ushort_t* Ag = A + (size_t)(bm * 128 + srow) * K + schunk * 8;
    const ushort_t* Bg = B + (size_t)(bn * 128 + srow) * K + schunk * 8;
    const int sdst = tid * 8;                // LDS ushort offset

    // fragment LDS ushort offsets (k-invariant, read-side XOR)
    int a_off[2][4], b_off[2][4];
    #pragma unroll
    for (int h = 0; h < 2; h++)
        #pragma unroll
        for (int i = 0; i < 4; i++) {
            const int ra = wm + i * 16 + lr;
            a_off[h][i] = ra * 64 + (((h * 4 + lq) ^ (ra & 7)) * 8);
            const int rb = wn + i * 16 + lr;
            b_off[h][i] = rb * 64 + (((h * 4 + lq) ^ (rb & 7)) * 8);
        }

    const int iters = K >> 6;
    for (int t = 0; t < iters; ++t) {
        __syncthreads();   // all waves' reads of the buffer are done
        const size_t kk = (size_t)t * 64;
        #pragma unroll
        for (int i = 0; i < 4; i++)
            gload16(Ag + (size_t)i * 32 * K + kk, &As[sdst + i * 2048]);
        #pragma unroll
        for (int i = 0; i < 4; i++)
            gload16(Bg + (size_t)i * 32 * K + kk, &Bs[sdst + i * 2048]);
        __syncthreads();   // compiler-inserted vmcnt(0) drain -> tile landed
        #pragma unroll
        for (int h = 0; h < 2; h++) {
            v8s af[4], bfr[4];
            #pragma unroll
            for (int i = 0; i < 4; i++) af[i] = *(const v8s*)&As[a_off[h][i]];
            #pragma unroll
            for (int j = 0; j < 4; j++) bfr[j] = *(const v8s*)&Bs[b_off[h][j]];
            #pragma unroll
            for (int i = 0; i < 4; i++)
                #pragma unroll
                for (int j = 0; j < 4; j++)
                    acc[i][j] = __builtin_amdgcn_mfma_f32_16x16x32_bf16(af[i], bfr[j], acc[i][j], 0, 0, 0);
        }
    }

    // epilogue: C/D layout col = lane&15, row = (lane>>4)*4 + reg
    const int row0 = bm * 128 + wm + lq * 4;
    const int col0 = bn * 128 + wn + lr;

    const int seg = (EPI == EPI_QKV) ? (bn >> 3) : 0;   // 1024-col segments
    ushort_t* qkv_out = (EPI == EPI_QKV)
        ? (seg == 0 ? outB : (seg == 1 ? outB2 : outB3)) : outB;
    const float* qkv_bias = (EPI == EPI_QKV)
        ? (seg == 0 ? bias : (seg == 1 ? bias2 : bias3)) : bias;
    const int blen = (EPI == EPI_QKV) ? lens[bm >> 5] : 0;

    #pragma unroll
    for (int i = 0; i < 4; i++) {
        #pragma unroll
        for (int j = 0; j < 4; j++) {
            const int gn = col0 + j * 16;
            const float bsv = (EPI == EPI_QKV) ? qkv_bias[gn & 1023] : bias[gn];
            #pragma unroll
            for (int r = 0; r < 4; r++) {
                const int gm = row0 + i * 16 + r;
                float v = acc[i][j][r] + bsv;
                if (EPI == EPI_QKV) {
                    const size_t oi = (size_t)gm * DMODEL + (gn & 1023);
                    if (seg == 2) {
                        qkv_out[oi] = f2bf(v);                    // V
                    } else {
                        float e = v > 0.f ? v + 1.f : __expf(v);  // elu+1
                        if (seg == 1 && (gm & 4095) >= blen) e = 0.f;  // K mask
                        qkv_out[oi] = f2bf(e);
                    }
                } else if (EPI == EPI_RES) {
                    const size_t oi = (size_t)gm * N + gn;
                    outF[oi] = v + res[oi];
                } else {  // EPI_GELU
                    const size_t oi = (size_t)gm * N + gn;
                    outB[oi] = f2bf(gelu_f(v));
                }
            }
        }
    }
}

// ---------------------------------------------------------------------------
__global__ __launch_bounds__(256) void ksum_kernel(const ushort_t* __restrict__ K,
                                                   float* __restrict__ out) {
    const int blk = blockIdx.x;
    const int n = blk >> 4, cg = blk & 15;
    const int tx = threadIdx.x & 63, ty = threadIdx.x >> 6;
    const int col = cg * 64 + tx;
    const ushort_t* p = K + ((size_t)n * SEQ + ty * 1024) * DMODEL + col;
    float a = 0.f;
    for (int s = 0; s < 1024; s++) a += bf2f(p[(size_t)s * DMODEL]);
    __shared__ float red[4][64];
    red[ty][tx] = a;
    __syncthreads();
    if (ty == 0) out[n * DMODEL + col] = red[0][tx] + red[1][tx] + red[2][tx] + red[3][tx];
}

// ---------------------------------------------------------------------------
__global__ __launch_bounds__(256) void kv_part(const ushort_t* __restrict__ K,
                                               const ushort_t* __restrict__ V,
                                               float* __restrict__ part) {
    const int chunk = blockIdx.x, nh = blockIdx.y;
    const int n = nh >> 4, h = nh & 15;
    const int tid = threadIdx.x;
    const int tm = tid >> 4, td = tid & 15;
    __shared__ float Ks[16][68];
    __shared__ float Vs[16][68];
    float acc[4][4] = {};
    const int s0 = chunk * 512;
    for (int sb = 0; sb < 512; sb += 16) {
        __syncthreads();
        for (int idx = tid; idx < 1024; idx += 256) {
            const int r = idx >> 6, c = idx & 63;
            const size_t gpos = ((size_t)(n * SEQ + s0 + sb + r)) * DMODEL + h * HDIM + c;
            Ks[r][c] = bf2f(K[gpos]);
            Vs[r][c] = bf2f(V[gpos]);
        }
        __syncthreads();
        #pragma unroll
        for (int s = 0; s < 16; s++) {
            float kv[4], vv[4];
            #pragma unroll
            for (int j = 0; j < 4; j++) kv[j] = Ks[s][td * 4 + j];
            #pragma unroll
            for (int i = 0; i < 4; i++) vv[i] = Vs[s][tm * 4 + i];
            #pragma unroll
            for (int i = 0; i < 4; i++)
                #pragma unroll
                for (int j = 0; j < 4; j++)
                    acc[i][j] += vv[i] * kv[j];
        }
    }
    float* o = part + ((size_t)chunk * 64 + nh) * 4096;
    #pragma unroll
    for (int i = 0; i < 4; i++)
        #pragma unroll
        for (int j = 0; j < 4; j++)
            o[(tm * 4 + i) * 64 + td * 4 + j] = acc[i][j];
}

__global__ __launch_bounds__(256) void kv_reduce(const float* __restrict__ part,
                                                 float* __restrict__ KV) {
    const int gid = blockIdx.x * 256 + threadIdx.x;
    float a = 0.f;
    #pragma unroll
    for (int c = 0; c < 8; c++) a += part[(size_t)c * (64 * 4096) + gid];
    KV[gid] = a;
}

// ---------------------------------------------------------------------------
__global__ __launch_bounds__(256) void attn_kernel(const ushort_t* __restrict__ Q,
                                                   const float* __restrict__ KV,
                                                   const float* __restrict__ Ksum,
                                                   ushort_t* __restrict__ out) {
    const int bx = blockIdx.x, nh = blockIdx.y;
    const int n = nh >> 4, h = nh & 15;
    const int tid = threadIdx.x;
    const int ty = tid >> 4, tx = tid & 15;
    __shared__ float KVs[64][65];
    __shared__ float Qs[64][65];
    __shared__ float Zs[64];
    const int t0 = n * SEQ + bx * 64;
    for (int idx = tid; idx < 4096; idx += 256) {
        const int r = idx >> 6, c = idx & 63;
        KVs[r][c] = KV[(size_t)nh * 4096 + idx];
        Qs[r][c] = bf2f(Q[((size_t)(t0 + r)) * DMODEL + h * HDIM + c]);
    }
    __syncthreads();
    if (tid < 64) {
        const float* ks = Ksum + n * DMODEL + h * HDIM;
        float a = 0.f;
        #pragma unroll
        for (int d = 0; d < 64; d++) a += Qs[tid][d] * ks[d];
        Zs[tid] = 1.f / (a + 1e-6f);
    }
    __syncthreads();
    float acc[4][4] = {};
    for (int d = 0; d < 64; d++) {
        float qv[4], kv[4];
        #pragma unroll
        for (int i = 0; i < 4; i++) qv[i] = Qs[ty * 4 + i][d];
        #pragma unroll
        for (int j = 0; j < 4; j++) kv[j] = KVs[tx * 4 + j][d];
        #pragma unroll
        for (int i = 0; i < 4; i++)
            #pragma unroll
            for (int j = 0; j < 4; j++)
                acc[i][j] += qv[i] * kv[j];
    }
    #pragma unroll
    for (int i = 0; i < 4; i++) {
        const int r = ty * 4 + i;
        const float z = Zs[r];
        v4u o;
        #pragma unroll
        for (int j = 0; j < 4; j++) o[j] = f2bf(acc[i][j] * z);
        *(v4u*)&out[((size_t)(t0 + r)) * DMODEL + h * HDIM + tx * 4] = o;  // 8B store
    }
}

// ---------------------------------------------------------------------------
__global__ __launch_bounds__(256) void ln_kernel(const float* in, float* outF,
                                                 ushort_t* outB,
                                                 const float* __restrict__ g,
                                                 const float* __restrict__ b) {
    const int row = blockIdx.x;
    const int tid = threadIdx.x;
    const float4 v = ((const float4*)(in + (size_t)row * DMODEL))[tid];
    float s = v.x + v.y + v.z + v.w;
    float ss = v.x * v.x + v.y * v.y + v.z * v.z + v.w * v.w;
    #pragma unroll
    for (int off = 32; off; off >>= 1) {
        s += __shfl_down(s, off);
        ss += __shfl_down(ss, off);
    }
    __shared__ float red[8];
    const int lane = tid & 63, w = tid >> 6;
    if (lane == 0) { red[w * 2] = s; red[w * 2 + 1] = ss; }
    __syncthreads();
    s = red[0] + red[2] + red[4] + red[6];
    ss = red[1] + red[3] + red[5] + red[7];
    const float mu = s * (1.f / DMODEL);
    const float var = ss * (1.f / DMODEL) - mu * mu;
    const float rs = rsqrtf(var + 1e-5f);
    const float4 gg = ((const float4*)g)[tid];
    const float4 bb = ((const float4*)b)[tid];
    float4 o;
    o.x = (v.x - mu) * rs * gg.x + bb.x;
    o.y = (v.y - mu) * rs * gg.y + bb.y;
    o.z = (v.z - mu) * rs * gg.z + bb.z;
    o.w = (v.w - mu) * rs * gg.w + bb.w;
    ((float4*)(outF + (size_t)row * DMODEL))[tid] = o;
    if (outB) {
        v4u ob;
        ob[0] = f2bf(o.x); ob[1] = f2bf(o.y); ob[2] = f2bf(o.z); ob[3] = f2bf(o.w);
        *(v4u*)(outB + (size_t)row * DMODEL + tid * 4) = ob;
    }
}

// ---------------------------------------------------------------------------
extern "C" void kernel_launch(void* const* d_in, const int* in_sizes, int n_in,
                              void* d_out, int out_size, void* d_ws, size_t ws_size,
                              hipStream_t stream) {
    const float* src = (const float*)d_in[0];
    const unsigned char* mask = (const unsigned char*)d_in[1];
    const float* Wq = (const float*)d_in[2];
    const float* bq = (const float*)d_in[3];
    const float* Wk = (const float*)d_in[4];
    const float* bk = (const float*)d_in[5];
    const float* Wv = (const float*)d_in[6];
    const float* bv = (const float*)d_in[7];
    const float* Wo = (const float*)d_in[8];
    const float* bo = (const float*)d_in[9];
    const float* W1 = (const float*)d_in[10];
    const float* b1 = (const float*)d_in[11];
    const float* W2 = (const float*)d_in[12];
    const float* b2 = (const float*)d_in[13];
    const float* g1 = (const float*)d_in[14];
    const float* be1 = (const float*)d_in[15];
    const float* g2 = (const float*)d_in[16];
    const float* be2 = (const float*)d_in[17];

    float* xout = (float*)d_out;  // fp32 residual-stream master

    char* ws = (char*)d_ws;
    size_t off = 0;
    auto alloc = [&](size_t bytes) -> void* {
        void* p = (void*)(ws + off);
        off += (bytes + 255) & ~(size_t)255;
        return p;
    };
    const size_t DD = (size_t)DMODEL * DMODEL;
    const size_t FD = (size_t)DFF * DMODEL;
    const size_t MD = (size_t)MTOK * DMODEL;

    ushort_t* wqkv_bf = (ushort_t*)alloc(NLAYER * 3 * DD * 2);  // [L][3][D][D]
    ushort_t* wo_bf = (ushort_t*)alloc(NLAYER * DD * 2);
    ushort_t* w1r = (ushort_t*)alloc(FD * 2);
    ushort_t* w2r = (ushort_t*)alloc(FD * 2);
    ushort_t* xbf = (ushort_t*)alloc(MD * 2);
    ushort_t* Qb = (ushort_t*)alloc(MD * 2);
    ushort_t* Kb = (ushort_t*)alloc(MD * 2);
    ushort_t* Vb = (ushort_t*)alloc(MD * 2);
    (void)alloc(MD * 2);          // hb (=Qb) overlay spans MTOK*DFF bf16
    ushort_t* hb = Qb;
    float* Ksum = (float*)alloc((size_t)NBATCH * DMODEL * 4);
    float* KVp = (float*)alloc((size_t)8 * 64 * 4096 * 4);
    float* KVb = (float*)alloc((size_t)64 * 4096 * 4);
    int* lens = (int*)alloc(256);
    if (off > ws_size) return;

    cvt_qkv<<<dim3((unsigned)((NLAYER * DD) / 1024)), dim3(256), 0, stream>>>(Wq, Wk, Wv, wqkv_bf);
    cvt_bf16<<<dim3((unsigned)((NLAYER * DD) / 1024)), dim3(256), 0, stream>>>(Wo, wo_bf, (int)(NLAYER * DD));
    lens_kernel<<<dim3(1), dim3(256), 0, stream>>>(mask, lens);
    cvt_bf16<<<dim3((unsigned)(MD / 1024)), dim3(256), 0, stream>>>(src, xbf, (int)MD);

    const dim3 blk(256);
    const dim3 gQKV((MTOK / 128) * (3 * DMODEL / 128));  // 3072 blocks
    const dim3 gD((MTOK / 128) * (DMODEL / 128));        // 1024 blocks
    const dim3 gF((MTOK / 128) * (DFF / 128));           // 4096 blocks

    for (int l = 0; l < NLAYER; l++) {
        const ushort_t* wqkvl = wqkv_bf + (size_t)l * 3 * DD;
        const ushort_t* wol = wo_bf + l * DD;
        const float* bql = bq + l * DMODEL;
        const float* bkl = bk + l * DMODEL;
        const float* bvl = bv + l * DMODEL;
        const float* bol = bo + l * DMODEL;
        const float* b1l = b1 + l * DFF;
        const float* b2l = b2 + l * DMODEL;
        const float* g1l = g1 + l * DMODEL;
        const float* be1l = be1 + l * DMODEL;
        const float* g2l = g2 + l * DMODEL;
        const float* be2l = be2 + l * DMODEL;
        const float* resx = (l == 0) ? src : xout;

        // fused Q/K/V projection with feature map + mask
        gemm_bt<EPI_QKV><<<gQKV, blk, 0, stream>>>(xbf, wqkvl, bql, bkl, bvl,
            nullptr, lens, Qb, Kb, Vb, nullptr, MTOK, 3 * DMODEL, DMODEL);

        // linear-attention core
        ksum_kernel<<<dim3(64), blk, 0, stream>>>(Kb, Ksum);
        kv_part<<<dim3(8, 64), blk, 0, stream>>>(Kb, Vb, KVp);
        kv_reduce<<<dim3(64 * 4096 / 256), blk, 0, stream>>>(KVp, KVb);
        attn_kernel<<<dim3(64, 64), blk, 0, stream>>>(Qb, KVb, Ksum, Kb);  // attn -> Kb

        // output projection + residual (fp32), then LN1 + bf16 copy
        gemm_bt<EPI_RES><<<gD, blk, 0, stream>>>(Kb, wol, bol, nullptr, nullptr,
            resx, lens, nullptr, nullptr, nullptr, xout, MTOK, DMODEL, DMODEL);
        ln_kernel<<<dim3(MTOK), blk, 0, stream>>>(xout, xout, xbf, g1l, be1l);

        // FFN
        cvt_bf16<<<dim3((unsigned)(FD / 1024)), blk, 0, stream>>>(W1 + l * FD, w1r, (int)FD);
        gemm_bt<EPI_GELU><<<gF, blk, 0, stream>>>(xbf, w1r, b1l, nullptr, nullptr,
            nullptr, lens, hb, nullptr, nullptr, nullptr, MTOK, DFF, DMODEL);
        cvt_bf16<<<dim3((unsigned)(FD / 1024)), blk, 0, stream>>>(W2 + l * FD, w2r, (int)FD);
        gemm_bt<EPI_RES><<<gD, blk, 0, stream>>>(hb, w2r, b2l, nullptr, nullptr,
            xout, lens, nullptr, nullptr, nullptr, xout, MTOK, DMODEL, DFF);
        ln_kernel<<<dim3(MTOK), blk, 0, stream>>>(xout, xout, (l == NLAYER - 1) ? nullptr : xbf, g2l, be2l);
    }
}